// Round 4
// baseline (106.753 us; speedup 1.0000x reference)
//
#include <hip/hip_runtime.h>

#define GRID_W 4
#define GRID_H 4
#define NEXP   16
#define HID    256
#define TPB    1024
#define S      2          // samples per thread
#define ESTRIDE 1540      // floats per expert in LDS: 1536 + 4 pad.
                          // 1540 % 32 == 4 -> for fixed k, the 16 experts' reads
                          // start at banks {4e+k}%32: max 2 distinct addrs/bank
                          // (2-way is free, m136). 1540 % 4 == 0 keeps float4 align.

// One fused kernel: ALL 16 experts' weights (98.5 KB) fit in LDS, so no
// routing/bucketing/multi-dispatch is needed at all. Each thread computes its
// own samples' experts and reads that expert's weights from LDS (divergent but
// conflict-free by construction). Single dispatch, no ws, no atomics.
__global__ __launch_bounds__(TPB, 4) void fused_moe_kernel(
    const float2* __restrict__ samples,
    const float*  __restrict__ W1, const float* __restrict__ b1,
    const float*  __restrict__ W2, const float* __restrict__ b2,
    float* __restrict__ out, int N)
{
    extern __shared__ float sW[];          // [NEXP*ESTRIDE] weights + [48] b2
    float* sB2 = sW + NEXP * ESTRIDE;
    const int tid = threadIdx.x;

    // ---- stage all experts' weights into LDS (coalesced float4) ----
    // per expert: [0,512)=W1 (row0 then row1), [512,768)=b1, [768,1536)=W2[k][3]
    for (int t = tid; t < NEXP * 128; t += TPB) {
        int e = t >> 7, r = t & 127;
        ((float4*)(sW + e * ESTRIDE))[r] = ((const float4*)(W1 + e * (2 * HID)))[r];
    }
    for (int t = tid; t < NEXP * 64; t += TPB) {
        int e = t >> 6, r = t & 63;
        ((float4*)(sW + e * ESTRIDE + 512))[r] = ((const float4*)(b1 + e * HID))[r];
    }
    for (int t = tid; t < NEXP * 192; t += TPB) {
        int e = t / 192, r = t - e * 192;
        ((float4*)(sW + e * ESTRIDE + 768))[r] = ((const float4*)(W2 + e * (3 * HID)))[r];
    }
    if (tid < NEXP * 3) sB2[tid] = b2[tid];
    __syncthreads();

    const int gid0 = blockIdx.x * (TPB * S) + tid;

    int   gid[S], wbase[S];
    bool  act[S];
    float px[S], py[S], y0[S], y1[S], y2[S];

#pragma unroll
    for (int s = 0; s < S; ++s) {
        gid[s] = gid0 + s * TPB;                  // coalesced float2 loads
        act[s] = gid[s] < N;
        int g = act[s] ? gid[s] : 0;
        float2 p = samples[g];
        px[s] = p.x; py[s] = p.y;
        int i = (int)(p.x * (float)GRID_W); i = i < 0 ? 0 : (i > GRID_W - 1 ? GRID_W - 1 : i);
        int j = (int)(p.y * (float)GRID_H); j = j < 0 ? 0 : (j > GRID_H - 1 ? GRID_H - 1 : j);
        int e = j * GRID_W + i;
        wbase[s] = e * ESTRIDE;
        y0[s] = sB2[3 * e + 0];
        y1[s] = sB2[3 * e + 1];
        y2[s] = sB2[3 * e + 2];
    }

    // ---- MLP: per 4-k batch per sample: 6 ds_read_b128 + 24 fma/max ----
#pragma unroll 2
    for (int k = 0; k < HID; k += 4) {
        float A[S][4], B[S][4], C[S][4], U[S][12];
#pragma unroll
        for (int s = 0; s < S; ++s) {
            const float* W = sW + wbase[s];
            *(float4*)&A[s][0] = *(const float4*)(W + k);            // w1 row x
            *(float4*)&B[s][0] = *(const float4*)(W + 256 + k);      // w1 row y
            *(float4*)&C[s][0] = *(const float4*)(W + 512 + k);      // b1
            const float* Up = W + 768 + 3 * k;                       // w2[k][3]
            *(float4*)&U[s][0] = *(const float4*)(Up);
            *(float4*)&U[s][4] = *(const float4*)(Up + 4);
            *(float4*)&U[s][8] = *(const float4*)(Up + 8);
        }
#pragma unroll
        for (int s = 0; s < S; ++s) {
#pragma unroll
            for (int kk = 0; kk < 4; ++kk) {
                float h = fmaf(py[s], B[s][kk], C[s][kk]);
                h = fmaf(px[s], A[s][kk], h);
                h = fmaxf(h, 0.f);
                y0[s] = fmaf(h, U[s][3 * kk + 0], y0[s]);
                y1[s] = fmaf(h, U[s][3 * kk + 1], y1[s]);
                y2[s] = fmaf(h, U[s][3 * kk + 2], y2[s]);
            }
        }
    }

#pragma unroll
    for (int s = 0; s < S; ++s) {
        if (act[s]) {
            int i3 = 3 * gid[s];
            out[i3 + 0] = y0[s];
            out[i3 + 1] = y1[s];
            out[i3 + 2] = y2[s];
        }
    }
}

// ---------------------------------------------------------------------------
extern "C" void kernel_launch(void* const* d_in, const int* in_sizes, int n_in,
                              void* d_out, int out_size, void* d_ws, size_t ws_size,
                              hipStream_t stream) {
    const float* samples = (const float*)d_in[0];
    const float* W1      = (const float*)d_in[1];
    const float* b1      = (const float*)d_in[2];
    const float* W2      = (const float*)d_in[3];
    const float* b2      = (const float*)d_in[4];
    float* out = (float*)d_out;

    const int N = in_sizes[0] / 2;
    const int nblocks = (N + TPB * S - 1) / (TPB * S);     // 256 @ N=524288
    const size_t lds_bytes = (NEXP * ESTRIDE + NEXP * 3) * sizeof(float); // 98752

    fused_moe_kernel<<<nblocks, TPB, lds_bytes, stream>>>(
        (const float2*)samples, W1, b1, W2, b2, out, N);
}

// Round 5
// 101.030 us; speedup vs baseline: 1.0566x; 1.0566x over previous
//
#include <hip/hip_runtime.h>

#define GRID_W 4
#define GRID_H 4
#define NEXP   16
#define HID    256
#define TPB    1024
#define S      2
#define SAMP   (TPB * S)          // 2048 samples per block
#define NWAVE  (TPB / 64)         // 16 waves
#define WFLT   (6 * HID)          // 1536 floats of weights per expert
#define MAXENT 40                 // >= 16 + SAMP/128 = 32

// ---- LDS layout (units: floats / ints, both 4B) ----
#define OFF_W     0                               // [16][1536] expert weights
#define OFF_B2    (NEXP * WFLT)                   // 24576: [16][3] b2
#define OFF_SLOT  (OFF_B2 + NEXP * 3 + 1)         // 24625.. pad to float4:
#define OFF_SLOT4 ((OFF_SLOT + 3) & ~3)           // 24628 -> float4-aligned
#define NSLOT     (SAMP + 128)                    // +128: dual-entry overread pad
#define OFF_HIST  (OFF_SLOT4 + NSLOT * 4)         // ints from here on
#define OFF_OFF   (OFF_HIST + NEXP)               // off[17]
#define OFF_ES    (OFF_OFF + NEXP + 1)            // estart[17]
#define OFF_EEXP  (OFF_ES + NEXP + 1)
#define OFF_EBASE (OFF_EEXP + MAXENT)
#define OFF_ECNT  (OFF_EBASE + MAXENT)
#define OFF_C     (OFF_ECNT + MAXENT)
#define LDS_WORDS (OFF_C + 1)                     // ~33.5K words = ~134 KB

// Per-expert LDS weight layout: [0,256)=W1 row x, [256,512)=W1 row y,
// [512,768)=b1, [768,1536)=W2[k][3].
template<int SS>
__device__ __forceinline__ void mlp_run(const float* __restrict__ W,
                                        const float* px, const float* py,
                                        float (*y)[3]) {
#pragma unroll 2
    for (int k = 0; k < HID; k += 4) {
        float wa[4], wb[4], bb[4], u[12];
        *(float4*)wa    = *(const float4*)(W + k);               // uniform -> broadcast
        *(float4*)wb    = *(const float4*)(W + HID + k);
        *(float4*)bb    = *(const float4*)(W + 2 * HID + k);
        *(float4*)&u[0] = *(const float4*)(W + 3 * HID + 3 * k);
        *(float4*)&u[4] = *(const float4*)(W + 3 * HID + 3 * k + 4);
        *(float4*)&u[8] = *(const float4*)(W + 3 * HID + 3 * k + 8);
#pragma unroll
        for (int kk = 0; kk < 4; ++kk) {
#pragma unroll
            for (int s = 0; s < SS; ++s) {
                float h = fmaf(py[s], wb[kk], bb[kk]);
                h = fmaf(px[s], wa[kk], h);
                h = fmaxf(h, 0.f);
                y[s][0] = fmaf(h, u[3 * kk + 0], y[s][0]);
                y[s][1] = fmaf(h, u[3 * kk + 1], y[s][1]);
                y[s][2] = fmaf(h, u[3 * kk + 2], y[s][2]);
            }
        }
    }
}

__global__ __launch_bounds__(TPB, 4) void fused_sorted_moe_kernel(
    const float2* __restrict__ samples,
    const float*  __restrict__ W1, const float* __restrict__ b1,
    const float*  __restrict__ W2, const float* __restrict__ b2,
    float* __restrict__ out, int N)
{
    extern __shared__ float smem[];
    float*  sW    = smem + OFF_W;
    float*  sB2   = smem + OFF_B2;
    float4* sSlot = (float4*)(smem + OFF_SLOT4);
    int*    sHist = (int*)smem + OFF_HIST;
    int*    sOff  = (int*)smem + OFF_OFF;
    int*    sES   = (int*)smem + OFF_ES;
    int*    sEexp = (int*)smem + OFF_EEXP;
    int*    sEbas = (int*)smem + OFF_EBASE;
    int*    sEcnt = (int*)smem + OFF_ECNT;
    int*    sC    = (int*)smem + OFF_C;

    const int tid = threadIdx.x;

    // ---- S0: init histogram + stage all experts' weights (coalesced f4) ----
    if (tid < NEXP) sHist[tid] = 0;
    for (int t = tid; t < NEXP * 128; t += TPB) {           // W1: 2048 f4
        int e = t >> 7, r = t & 127;
        ((float4*)(sW + e * WFLT))[r] = ((const float4*)(W1 + e * (2 * HID)))[r];
    }
    for (int t = tid; t < NEXP * 64; t += TPB) {            // b1: 1024 f4
        int e = t >> 6, r = t & 63;
        ((float4*)(sW + e * WFLT + 2 * HID))[r] = ((const float4*)(b1 + e * HID))[r];
    }
    for (int t = tid; t < NEXP * 192; t += TPB) {           // W2: 3072 f4
        int e = t / 192, r = t - e * 192;
        ((float4*)(sW + e * WFLT + 3 * HID))[r] = ((const float4*)(W2 + e * (3 * HID)))[r];
    }
    if (tid < NEXP * 3) sB2[tid] = b2[tid];
    __syncthreads();

    // ---- S1: load samples, histogram via LDS atomics ----
    const int base0 = blockIdx.x * SAMP;
    float px[S], py[S]; int eid[S], rank[S], gid[S]; bool act[S];
#pragma unroll
    for (int s = 0; s < S; ++s) {
        gid[s] = base0 + s * TPB + tid;                     // coalesced float2
        act[s] = gid[s] < N;
        float2 p = act[s] ? samples[gid[s]] : make_float2(0.f, 0.f);
        px[s] = p.x; py[s] = p.y;
        int i = (int)(p.x * (float)GRID_W); i = i < 0 ? 0 : (i > GRID_W - 1 ? GRID_W - 1 : i);
        int j = (int)(p.y * (float)GRID_H); j = j < 0 ? 0 : (j > GRID_H - 1 ? GRID_H - 1 : j);
        eid[s] = j * GRID_W + i;
        rank[s] = act[s] ? atomicAdd(&sHist[eid[s]], 1) : 0;
    }
    __syncthreads();

    // ---- S2: tiny scans (thread 0): sample offsets + 128-granular entries ----
    if (tid == 0) {
        int acc = 0, ec = 0;
        for (int e = 0; e < NEXP; ++e) {
            sOff[e] = acc; acc += sHist[e];
            sES[e] = ec;  ec  += (sHist[e] + 127) >> 7;     // ceil(cnt/128) entries
        }
        sOff[NEXP] = acc; sES[NEXP] = ec; *sC = ec;
    }
    __syncthreads();

    // ---- S3: scatter sorted slots + build entry table ----
#pragma unroll
    for (int s = 0; s < S; ++s) {
        if (act[s]) {
            float4 v; v.x = px[s]; v.y = py[s];
            v.z = __int_as_float(gid[s]); v.w = 0.f;
            sSlot[sOff[eid[s]] + rank[s]] = v;
        }
    }
    int C = *sC;
    if (tid < C) {
        int e = 0;
        while (tid >= sES[e + 1]) ++e;                      // <=16 iters, once
        int j = tid - sES[e];
        sEexp[tid] = e;
        sEbas[tid] = sOff[e] + j * 128;
        sEcnt[tid] = min(128, sHist[e] - j * 128);
    }
    __syncthreads();

    // ---- Phase 2: expert-uniform chunks; weights broadcast from LDS ----
    const int lane = tid & 63, wv = tid >> 6;
    for (int c = wv; c < C; c += NWAVE) {
        int e    = __builtin_amdgcn_readfirstlane(sEexp[c]);
        int bas  = __builtin_amdgcn_readfirstlane(sEbas[c]);
        int cnt  = __builtin_amdgcn_readfirstlane(sEcnt[c]);
        const float* W = sW + e * WFLT;
        float b20 = sB2[3 * e], b21 = sB2[3 * e + 1], b22 = sB2[3 * e + 2];

        float qx[2], qy[2], yy[2][3]; int qg[2];
        float4 v0 = sSlot[bas + lane];                      // in-bounds (NSLOT pad)
        qx[0] = v0.x; qy[0] = v0.y; qg[0] = __float_as_int(v0.z);
        yy[0][0] = b20; yy[0][1] = b21; yy[0][2] = b22;

        if (cnt > 64) {                                     // dual: 128 samples/wave
            float4 v1 = sSlot[bas + 64 + lane];
            qx[1] = v1.x; qy[1] = v1.y; qg[1] = __float_as_int(v1.z);
            yy[1][0] = b20; yy[1][1] = b21; yy[1][2] = b22;
            mlp_run<2>(W, qx, qy, yy);
            { int i3 = 3 * qg[0];                           // sample0 always active
              out[i3] = yy[0][0]; out[i3 + 1] = yy[0][1]; out[i3 + 2] = yy[0][2]; }
            if (64 + lane < cnt) {
                int i3 = 3 * qg[1];
                out[i3] = yy[1][0]; out[i3 + 1] = yy[1][1]; out[i3 + 2] = yy[1][2];
            }
        } else {                                            // single (tail) chunk
            mlp_run<1>(W, qx, qy, yy);
            if (lane < cnt) {
                int i3 = 3 * qg[0];
                out[i3] = yy[0][0]; out[i3 + 1] = yy[0][1]; out[i3 + 2] = yy[0][2];
            }
        }
    }
}

// ---------------------------------------------------------------------------
extern "C" void kernel_launch(void* const* d_in, const int* in_sizes, int n_in,
                              void* d_out, int out_size, void* d_ws, size_t ws_size,
                              hipStream_t stream) {
    const float* samples = (const float*)d_in[0];
    const float* W1      = (const float*)d_in[1];
    const float* b1      = (const float*)d_in[2];
    const float* W2      = (const float*)d_in[3];
    const float* b2      = (const float*)d_in[4];
    float* out = (float*)d_out;

    const int N = in_sizes[0] / 2;
    const int nblocks = (N + SAMP - 1) / SAMP;              // 256 @ N=524288
    const size_t lds_bytes = (size_t)LDS_WORDS * 4;         // ~134 KB (<160 KB)

    fused_sorted_moe_kernel<<<nblocks, TPB, lds_bytes, stream>>>(
        (const float2*)samples, W1, b1, W2, b2, out, N);
}

// Round 6
// 85.717 us; speedup vs baseline: 1.2454x; 1.1786x over previous
//
#include <hip/hip_runtime.h>

typedef _Float16 h2 __attribute__((ext_vector_type(2)));

#define GRID_W 4
#define GRID_H 4
#define NEXP   16
#define HID    256
#define TPB    1024
#define S      2
#define SAMP   (TPB * S)            // 2048 samples per block
#define NWAVE  (TPB / 64)           // 16 waves
#define WPE    1536                 // halves per expert in LDS
#define GR     192                  // entry granularity (SS_MAX=3 * 64)
#define MAXENT 32

// ---- LDS byte-offset map (total 67856 B -> 2 blocks/CU fit in 160 KB) ----
// [0,      49152): _Float16 weights [16][1536]
//                  per-expert half-offsets: WA=0, WB=256, B1=512, U0=768, U1=1024, U2=1280
// [49152,  49344): float sB2[48]
// [49344,  67264): int2 slots[2048+192]   ({half2(x,y), gid}; +192 overread pad)
// [67264,  67852): ints: hist[16], off[17], es[17], eexp[32], ebas[32], ecnt[32], C
#define OFFB_B2   49152
#define OFFB_SLOT 49344
#define OFFB_INT  67264
#define LDS_BYTES 67856

// Per 16-B LDS read: 8 fp16 weights = 4 k-pairs.
union H8 { float4 f; h2 p[4]; };

template<int M>
__device__ __forceinline__ void mlp_fp16(const _Float16* __restrict__ W,
                                         const h2* px2, const h2* py2,
                                         float (*y)[3]) {
    const float4* W4 = (const float4*)W;   // 16-B units within this expert
#pragma unroll 2
    for (int b = 0; b < 32; ++b) {         // 8 k's per batch
        H8 wa, wb, bb, u0, u1, u2;
        wa.f = W4[b];        // W1 row x
        wb.f = W4[32 + b];   // W1 row y
        bb.f = W4[64 + b];   // b1
        u0.f = W4[96 + b];   // W2 col 0 (k-major)
        u1.f = W4[128 + b];  // W2 col 1
        u2.f = W4[160 + b];  // W2 col 2
#pragma unroll
        for (int j = 0; j < 4; ++j) {
#pragma unroll
            for (int s = 0; s < M; ++s) {
                h2 h = __builtin_elementwise_fma(px2[s], wa.p[j],
                       __builtin_elementwise_fma(py2[s], wb.p[j], bb.p[j]));
                h2 z = (h2)(_Float16)0.0f;
                h = __builtin_elementwise_max(h, z);       // v_pk_max_f16
#if __has_builtin(__builtin_amdgcn_fdot2)
                y[s][0] = __builtin_amdgcn_fdot2(h, u0.p[j], y[s][0], false);
                y[s][1] = __builtin_amdgcn_fdot2(h, u1.p[j], y[s][1], false);
                y[s][2] = __builtin_amdgcn_fdot2(h, u2.p[j], y[s][2], false);
#else
                y[s][0] += (float)h.x * (float)u0.p[j].x + (float)h.y * (float)u0.p[j].y;
                y[s][1] += (float)h.x * (float)u1.p[j].x + (float)h.y * (float)u1.p[j].y;
                y[s][2] += (float)h.x * (float)u2.p[j].x + (float)h.y * (float)u2.p[j].y;
#endif
            }
        }
    }
}

__global__ __launch_bounds__(TPB, 8) void fused_fp16_moe_kernel(
    const float2* __restrict__ samples,
    const float*  __restrict__ W1, const float* __restrict__ b1,
    const float*  __restrict__ W2, const float* __restrict__ b2,
    float* __restrict__ out, int N)
{
    extern __shared__ __align__(16) char smem[];
    _Float16* sWgt = (_Float16*)smem;
    float*    sB2  = (float*)(smem + OFFB_B2);
    int2*     sSlot= (int2*)(smem + OFFB_SLOT);
    int*      sI   = (int*)(smem + OFFB_INT);
    int* sHist = sI;        // [16]
    int* sOff  = sI + 16;   // [17]
    int* sES   = sI + 33;   // [17]
    int* sEexp = sI + 50;   // [32]
    int* sEbas = sI + 82;   // [32]
    int* sEcnt = sI + 114;  // [32]
    int* sC    = sI + 146;

    const int tid = threadIdx.x;

    // ---- S0: init hist + stage all weights fp32->fp16 into LDS ----
    if (tid < NEXP) sHist[tid] = 0;
    // W1 + b1: one (e, k-pair) task per thread-step; coalesced float2 reads
    for (int t = tid; t < NEXP * 128; t += TPB) {
        int e = t >> 7, k2 = t & 127;
        const float2* ga = (const float2*)(W1 + e * 512);
        const float2* gb = (const float2*)(W1 + e * 512 + 256);
        const float2* gc = (const float2*)(b1 + e * 256);
        float2 A = ga[k2], B = gb[k2], Cc = gc[k2];
        h2* base = (h2*)(sWgt + e * WPE);
        h2 pa; pa.x = (_Float16)A.x;  pa.y = (_Float16)A.y;
        h2 pb; pb.x = (_Float16)B.x;  pb.y = (_Float16)B.y;
        h2 pc; pc.x = (_Float16)Cc.x; pc.y = (_Float16)Cc.y;
        base[k2]       = pa;    // WA
        base[128 + k2] = pb;    // WB
        base[256 + k2] = pc;    // B1
    }
    // W2: transpose [k][3] -> 3 k-major arrays while converting
    for (int t = tid; t < NEXP * 128; t += TPB) {
        int e = t >> 7, k2 = t & 127;
        const float2* g = (const float2*)(W2 + e * 768 + 6 * k2);
        float2 r0 = g[0], r1 = g[1], r2 = g[2];
        // memory: {u0[k],u1[k]} {u2[k],u0[k+1]} {u1[k+1],u2[k+1]}
        h2* base = (h2*)(sWgt + e * WPE);
        h2 p0; p0.x = (_Float16)r0.x; p0.y = (_Float16)r1.y;
        h2 p1; p1.x = (_Float16)r0.y; p1.y = (_Float16)r2.x;
        h2 p2; p2.x = (_Float16)r1.x; p2.y = (_Float16)r2.y;
        base[384 + k2] = p0;    // U0
        base[512 + k2] = p1;    // U1
        base[640 + k2] = p2;    // U2
    }
    if (tid < NEXP * 3) sB2[tid] = b2[tid];
    __syncthreads();

    // ---- S1: load samples, LDS histogram ----
    const int base0 = blockIdx.x * SAMP;
    float px[S], py[S]; int eid[S], rank[S], gid[S]; bool act[S];
#pragma unroll
    for (int s = 0; s < S; ++s) {
        gid[s] = base0 + s * TPB + tid;
        act[s] = gid[s] < N;
        float2 p = act[s] ? samples[gid[s]] : make_float2(0.f, 0.f);
        px[s] = p.x; py[s] = p.y;
        int i = (int)(p.x * (float)GRID_W); i = i < 0 ? 0 : (i > GRID_W - 1 ? GRID_W - 1 : i);
        int j = (int)(p.y * (float)GRID_H); j = j < 0 ? 0 : (j > GRID_H - 1 ? GRID_H - 1 : j);
        eid[s] = j * GRID_W + i;
        rank[s] = act[s] ? atomicAdd(&sHist[eid[s]], 1) : 0;
    }
    __syncthreads();

    // ---- S2: serial scans (thread 0): sample offsets + GR-granular entries ----
    if (tid == 0) {
        int acc = 0, ec = 0;
        for (int e = 0; e < NEXP; ++e) {
            sOff[e] = acc; acc += sHist[e];
            sES[e] = ec;  ec  += (sHist[e] + GR - 1) / GR;
        }
        sOff[NEXP] = acc; sES[NEXP] = ec; *sC = ec;
    }
    __syncthreads();

    // ---- S3: scatter sorted slots {half2(x,y), gid} + build entry table ----
#pragma unroll
    for (int s = 0; s < S; ++s) {
        if (act[s]) {
            union { h2 h; int i; } u;
            u.h.x = (_Float16)px[s]; u.h.y = (_Float16)py[s];
            int2 v; v.x = u.i; v.y = gid[s];
            sSlot[sOff[eid[s]] + rank[s]] = v;
        }
    }
    int C = *sC;
    if (tid < C) {
        int e = 0;
        while (tid >= sES[e + 1]) ++e;
        int j = tid - sES[e];
        sEexp[tid] = e;
        sEbas[tid] = sOff[e] + j * GR;
        sEcnt[tid] = min(GR, sHist[e] - j * GR);
    }
    __syncthreads();

    // ---- Phase 2: expert-uniform waves; fp16 weights broadcast from LDS ----
    const int lane = tid & 63, wv = tid >> 6;
    for (int c = wv; c < C; c += NWAVE) {
        int e   = __builtin_amdgcn_readfirstlane(sEexp[c]);
        int bas = __builtin_amdgcn_readfirstlane(sEbas[c]);
        int cnt = __builtin_amdgcn_readfirstlane(sEcnt[c]);
        const _Float16* W = sWgt + e * WPE;
        float b20 = sB2[3 * e], b21 = sB2[3 * e + 1], b22 = sB2[3 * e + 2];
        int m = (cnt + 63) >> 6;                      // 1..3

        h2 px2[3], py2[3]; int qg[3]; float yy[3][3];
#pragma unroll
        for (int s = 0; s < 3; ++s) {
            if (s < m) {
                int2 v = sSlot[bas + s * 64 + lane];  // pad makes this in-bounds
                union { int i; h2 h; } u; u.i = v.x;
                px2[s].x = u.h.x; px2[s].y = u.h.x;
                py2[s].x = u.h.y; py2[s].y = u.h.y;
                qg[s] = v.y;
                yy[s][0] = b20; yy[s][1] = b21; yy[s][2] = b22;
            }
        }

        if (m == 3)      mlp_fp16<3>(W, px2, py2, yy);
        else if (m == 2) mlp_fp16<2>(W, px2, py2, yy);
        else             mlp_fp16<1>(W, px2, py2, yy);

#pragma unroll
        for (int s = 0; s < 3; ++s) {
            if (s < m && s * 64 + lane < cnt) {
                int i3 = 3 * qg[s];
                out[i3 + 0] = yy[s][0];
                out[i3 + 1] = yy[s][1];
                out[i3 + 2] = yy[s][2];
            }
        }
    }
}

// ---------------------------------------------------------------------------
extern "C" void kernel_launch(void* const* d_in, const int* in_sizes, int n_in,
                              void* d_out, int out_size, void* d_ws, size_t ws_size,
                              hipStream_t stream) {
    const float* samples = (const float*)d_in[0];
    const float* W1      = (const float*)d_in[1];
    const float* b1      = (const float*)d_in[2];
    const float* W2      = (const float*)d_in[3];
    const float* b2      = (const float*)d_in[4];
    float* out = (float*)d_out;

    const int N = in_sizes[0] / 2;
    const int nblocks = (N + SAMP - 1) / SAMP;      // 256 @ N=524288

    fused_fp16_moe_kernel<<<nblocks, TPB, LDS_BYTES, stream>>>(
        (const float2*)samples, W1, b1, W2, b2, out, N);
}

// Round 7
// 85.042 us; speedup vs baseline: 1.2553x; 1.0079x over previous
//
#include <hip/hip_runtime.h>

typedef _Float16 h2 __attribute__((ext_vector_type(2)));

#define GRID_W 4
#define GRID_H 4
#define NEXP   16
#define HID    256
#define TPB    1024
#define S      2
#define SAMP   (TPB * S)            // 2048 samples per block
#define NWAVE  (TPB / 64)           // 16 waves
#define WPE    1536                 // fp16 halves per expert in ws (3072 B)
#define GR     192                  // entry granularity (up to 3 sub-waves)
#define MAXENT 32

// ---- LDS: only the sort structures now (~18.5 KB) ----
#define NSLOT  (SAMP + GR)          // +GR: sub-wave overread pad
#define OFFB_I (NSLOT * 8)          // ints start after int2 slots
#define LDS_BYTES (OFFB_I + 4 * (16 + 17 + 17 + 3 * MAXENT + 1))

// ---------------------------------------------------------------------------
// Kernel A: convert weights fp32 -> fp16 into d_ws, k-major per expert:
// [0,256)=W1 row x, [256,512)=W1 row y, [512,768)=b1,
// [768,1024)=W2 col0, [1024,1280)=W2 col1, [1280,1536)=W2 col2.
// ---------------------------------------------------------------------------
__global__ __launch_bounds__(256) void convert_kernel(
    const float* __restrict__ W1, const float* __restrict__ b1,
    const float* __restrict__ W2, _Float16* __restrict__ wsW) {
    int t = blockIdx.x * 256 + threadIdx.x;     // 4096 = NEXP*HID threads
    int e = t >> 8, k = t & 255;
    _Float16* dst = wsW + e * WPE;
    dst[k]        = (_Float16)W1[e * 512 + k];
    dst[256 + k]  = (_Float16)W1[e * 512 + 256 + k];
    dst[512 + k]  = (_Float16)b1[e * 256 + k];
    dst[768 + k]  = (_Float16)W2[e * 768 + 3 * k];
    dst[1024 + k] = (_Float16)W2[e * 768 + 3 * k + 1];
    dst[1280 + k] = (_Float16)W2[e * 768 + 3 * k + 2];
}

// Per 16-B uniform load: 8 fp16 weights = 4 k-pairs. Address is wave-uniform
// (expert id readfirstlane'd, k loop-uniform) -> scalar s_load on the SMEM
// pipe; dual-issues with VALU, zero LDS/vector-L1 pressure.
union H8 { float4 f; h2 p[4]; };

template<int M>
__device__ __forceinline__ void mlp_pass(const float4* __restrict__ W4,
                                         const h2* px2, const h2* py2,
                                         float (*y)[3]) {
#pragma unroll 4
    for (int b = 0; b < 32; ++b) {              // 8 k's per batch
        H8 wa, wb, bb, u0, u1, u2;
        wa.f = W4[b];         // W1 row x
        wb.f = W4[32 + b];    // W1 row y
        bb.f = W4[64 + b];    // b1
        u0.f = W4[96 + b];    // W2 col 0 (k-major)
        u1.f = W4[128 + b];   // W2 col 1
        u2.f = W4[160 + b];   // W2 col 2
#pragma unroll
        for (int j = 0; j < 4; ++j) {
#pragma unroll
            for (int s = 0; s < M; ++s) {
                h2 h = __builtin_elementwise_fma(px2[s], wa.p[j],
                       __builtin_elementwise_fma(py2[s], wb.p[j], bb.p[j]));
                h2 z = (h2)(_Float16)0.0f;
                h = __builtin_elementwise_max(h, z);
#if __has_builtin(__builtin_amdgcn_fdot2)
                y[s][0] = __builtin_amdgcn_fdot2(h, u0.p[j], y[s][0], false);
                y[s][1] = __builtin_amdgcn_fdot2(h, u1.p[j], y[s][1], false);
                y[s][2] = __builtin_amdgcn_fdot2(h, u2.p[j], y[s][2], false);
#else
                y[s][0] += (float)h.x * (float)u0.p[j].x + (float)h.y * (float)u0.p[j].y;
                y[s][1] += (float)h.x * (float)u1.p[j].x + (float)h.y * (float)u1.p[j].y;
                y[s][2] += (float)h.x * (float)u2.p[j].x + (float)h.y * (float)u2.p[j].y;
#endif
            }
        }
    }
}

// ---------------------------------------------------------------------------
// Kernel B: in-block counting sort (LDS) -> expert-uniform waves -> MLP with
// scalar-loaded fp16 weights from ws.
// ---------------------------------------------------------------------------
__global__ __launch_bounds__(TPB) void fused_smem_moe_kernel(
    const float2* __restrict__ samples,
    const _Float16* __restrict__ wsW,
    const float* __restrict__ b2,
    float* __restrict__ out, int N)
{
    extern __shared__ __align__(16) char smem[];
    int2* sSlot = (int2*)smem;
    int*  sI    = (int*)(smem + OFFB_I);
    int* sHist = sI;                 // [16]
    int* sOff  = sI + 16;            // [17]
    int* sES   = sI + 33;            // [17]
    int* sEexp = sI + 50;            // [32]
    int* sEbas = sI + 50 + MAXENT;   // [32]
    int* sEcnt = sI + 50 + 2 * MAXENT;
    int* sC    = sI + 50 + 3 * MAXENT;

    const int tid = threadIdx.x;
    if (tid < NEXP) sHist[tid] = 0;
    __syncthreads();

    // ---- S1: load samples, LDS histogram ----
    const int base0 = blockIdx.x * SAMP;
    float px[S], py[S]; int eid[S], rank[S], gid[S]; bool act[S];
#pragma unroll
    for (int s = 0; s < S; ++s) {
        gid[s] = base0 + s * TPB + tid;               // coalesced float2
        act[s] = gid[s] < N;
        float2 p = act[s] ? samples[gid[s]] : make_float2(0.f, 0.f);
        px[s] = p.x; py[s] = p.y;
        int i = (int)(p.x * (float)GRID_W); i = i < 0 ? 0 : (i > GRID_W - 1 ? GRID_W - 1 : i);
        int j = (int)(p.y * (float)GRID_H); j = j < 0 ? 0 : (j > GRID_H - 1 ? GRID_H - 1 : j);
        eid[s] = j * GRID_W + i;
        rank[s] = act[s] ? atomicAdd(&sHist[eid[s]], 1) : 0;
    }
    __syncthreads();

    // ---- S2: serial scans (thread 0) ----
    if (tid == 0) {
        int acc = 0, ec = 0;
        for (int e = 0; e < NEXP; ++e) {
            sOff[e] = acc; acc += sHist[e];
            sES[e] = ec;  ec  += (sHist[e] + GR - 1) / GR;
        }
        sOff[NEXP] = acc; sES[NEXP] = ec; *sC = ec;
    }
    __syncthreads();

    // ---- S3: scatter sorted slots {half2(x,y), gid} + entry table ----
#pragma unroll
    for (int s = 0; s < S; ++s) {
        if (act[s]) {
            union { h2 h; int i; } u;
            u.h.x = (_Float16)px[s]; u.h.y = (_Float16)py[s];
            int2 v; v.x = u.i; v.y = gid[s];
            sSlot[sOff[eid[s]] + rank[s]] = v;
        }
    }
    int C = *sC;
    if (tid < C) {
        int e = 0;
        while (tid >= sES[e + 1]) ++e;
        int j = tid - sES[e];
        sEexp[tid] = e;
        sEbas[tid] = sOff[e] + j * GR;
        sEcnt[tid] = min(GR, sHist[e] - j * GR);
    }
    __syncthreads();

    // ---- Phase 2: expert-uniform waves; weights via scalar loads from ws ----
    const int lane = tid & 63, wv = tid >> 6;
    for (int c = wv; c < C; c += NWAVE) {
        int e   = __builtin_amdgcn_readfirstlane(sEexp[c]);
        int bas = __builtin_amdgcn_readfirstlane(sEbas[c]);
        int cnt = __builtin_amdgcn_readfirstlane(sEcnt[c]);
        const float4* W4 = (const float4*)(wsW + e * WPE);   // uniform base
        float b20 = b2[3 * e], b21 = b2[3 * e + 1], b22 = b2[3 * e + 2];
        int m = (cnt + 63) >> 6;                             // 1..3 sub-waves

        h2 px2[3], py2[3]; int qg[3]; float yy[3][3];
#pragma unroll
        for (int s = 0; s < 3; ++s) {
            if (s < m) {
                int2 v = sSlot[bas + s * 64 + lane];         // pad: in-bounds
                union { int i; h2 h; } u; u.i = v.x;
                px2[s].x = u.h.x; px2[s].y = u.h.x;
                py2[s].x = u.h.y; py2[s].y = u.h.y;
                qg[s] = v.y;
                yy[s][0] = b20; yy[s][1] = b21; yy[s][2] = b22;
            }
        }

        if (m == 3)      mlp_pass<3>(W4, px2, py2, yy);
        else if (m == 2) mlp_pass<2>(W4, px2, py2, yy);
        else             mlp_pass<1>(W4, px2, py2, yy);

#pragma unroll
        for (int s = 0; s < 3; ++s) {
            if (s < m && s * 64 + lane < cnt) {
                int i3 = 3 * qg[s];
                out[i3 + 0] = yy[s][0];
                out[i3 + 1] = yy[s][1];
                out[i3 + 2] = yy[s][2];
            }
        }
    }
}

// ---------------------------------------------------------------------------
extern "C" void kernel_launch(void* const* d_in, const int* in_sizes, int n_in,
                              void* d_out, int out_size, void* d_ws, size_t ws_size,
                              hipStream_t stream) {
    const float* samples = (const float*)d_in[0];
    const float* W1      = (const float*)d_in[1];
    const float* b1      = (const float*)d_in[2];
    const float* W2      = (const float*)d_in[3];
    const float* b2      = (const float*)d_in[4];
    float* out = (float*)d_out;

    const int N = in_sizes[0] / 2;
    _Float16* wsW = (_Float16*)d_ws;                 // 49152 B used

    convert_kernel<<<NEXP, 256, 0, stream>>>(W1, b1, W2, wsW);

    const int nblocks = (N + SAMP - 1) / SAMP;       // 256 @ N=524288
    fused_smem_moe_kernel<<<nblocks, TPB, LDS_BYTES, stream>>>(
        (const float2*)samples, wsW, b2, out, N);
}